// Round 13
// baseline (598.315 us; speedup 1.0000x reference)
//
#include <hip/hip_runtime.h>

typedef unsigned int u32;
typedef unsigned short u16;
typedef __attribute__((ext_vector_type(8))) short bf16x8;
typedef __attribute__((ext_vector_type(4))) float f32x4;

__device__ __forceinline__ u16 f2b(float f){
  u32 x = __float_as_uint(f);
  u32 r = (x + 0x7fffu + ((x >> 16) & 1u)) >> 16;
  return (u16)r;
}
__device__ __forceinline__ float b2f(u16 h){ return __uint_as_float((u32)h << 16); }
__device__ __forceinline__ float bl(u32 u){ return __uint_as_float(u << 16); }
__device__ __forceinline__ float bh(u32 u){ return __uint_as_float(u & 0xffff0000u); }

// ---------- preprocessing ----------

__global__ void k_detect(const u32* __restrict__ ei, int n, u32* __restrict__ flag){
  int t = blockIdx.x * blockDim.x + threadIdx.x;
  u32 v = 0;
  if (t < n) v = ei[2 * t + 1];
  unsigned long long b = __ballot(v != 0u);
  if ((threadIdx.x & 63) == 0 && b) atomicOr(flag, 1u);
}

// fused: index convert + degree histogram + eattr -> bf16 (original order, coalesced)
__global__ void k_convhist(const int* __restrict__ ei, int* __restrict__ src, int* __restrict__ dst,
                           int* __restrict__ deg, const float* __restrict__ eattr,
                           u16* __restrict__ ea2, int E, const u32* __restrict__ flag){
  int e = blockIdx.x * blockDim.x + threadIdx.x;
  if (e >= E) return;
  bool is64 = (*flag == 0u);
  int s, d;
  if (is64){ s = ei[2 * e]; d = ei[2 * (E + e)]; }
  else     { s = ei[e];     d = ei[E + e]; }
  src[e] = s; dst[e] = d;
  atomicAdd(&deg[d], 1);
  const float4* srow = (const float4*)(eattr + (size_t)e * 32);
  u32 pk[16];
  #pragma unroll
  for (int i = 0; i < 8; i++){
    float4 v = srow[i];
    pk[2*i]   = (u32)f2b(v.x) | ((u32)f2b(v.y) << 16);
    pk[2*i+1] = (u32)f2b(v.z) | ((u32)f2b(v.w) << 16);
  }
  uint4* drow = (uint4*)(ea2 + (size_t)e * 32);
  drow[0] = make_uint4(pk[0], pk[1], pk[2], pk[3]);
  drow[1] = make_uint4(pk[4], pk[5], pk[6], pk[7]);
  drow[2] = make_uint4(pk[8], pk[9], pk[10], pk[11]);
  drow[3] = make_uint4(pk[12], pk[13], pk[14], pk[15]);
}

// hierarchical scan
__global__ __launch_bounds__(256) void k_scan1(const int* __restrict__ deg, int* __restrict__ bsum, int n){
  int b = blockIdx.x, t = threadIdx.x, lane = t & 63, wv = t >> 6;
  int i0 = b * 1024 + t * 4;
  int4 v = make_int4(0,0,0,0);
  if (i0 + 3 < n) v = *(const int4*)(deg + i0);
  else { if (i0 < n) v.x = deg[i0]; if (i0+1 < n) v.y = deg[i0+1]; if (i0+2 < n) v.z = deg[i0+2]; }
  int s = v.x + v.y + v.z + v.w;
  #pragma unroll
  for (int off = 1; off < 64; off <<= 1) s += __shfl_xor(s, off);
  __shared__ int ws[4];
  if (lane == 0) ws[wv] = s;
  __syncthreads();
  if (t == 0) bsum[b] = ws[0] + ws[1] + ws[2] + ws[3];
}

__global__ __launch_bounds__(1024) void k_scan2(int* __restrict__ bsum, int nb, int* __restrict__ segN){
  int t = threadIdx.x, lane = t & 63, w = t >> 6;
  int v = (t < nb) ? bsum[t] : 0;
  int x = v;
  #pragma unroll
  for (int off = 1; off < 64; off <<= 1){
    int y = __shfl_up(x, off);
    if (lane >= off) x += y;
  }
  __shared__ int wsum[16];
  if (lane == 63) wsum[w] = x;
  __syncthreads();
  if (w == 0 && lane < 16){
    int sv = wsum[lane];
    #pragma unroll
    for (int off = 1; off < 16; off <<= 1){
      int y = __shfl_up(sv, off);
      if (lane >= off) sv += y;
    }
    wsum[lane] = sv;
  }
  __syncthreads();
  int woff = (w > 0) ? wsum[w - 1] : 0;
  if (t < nb) bsum[t] = woff + x - v;
  if (t == 0) *segN = wsum[15];
}

__global__ __launch_bounds__(256) void k_scan3(const int* __restrict__ deg, const int* __restrict__ bsum,
                                               int* __restrict__ seg, int n){
  int b = blockIdx.x, t = threadIdx.x, lane = t & 63, wv = t >> 6;
  int i0 = b * 1024 + t * 4;
  int4 v = make_int4(0,0,0,0);
  if (i0 + 3 < n) v = *(const int4*)(deg + i0);
  else { if (i0 < n) v.x = deg[i0]; if (i0+1 < n) v.y = deg[i0+1]; if (i0+2 < n) v.z = deg[i0+2]; }
  int s = v.x + v.y + v.z + v.w;
  int x = s;
  #pragma unroll
  for (int off = 1; off < 64; off <<= 1){
    int y = __shfl_up(x, off);
    if (lane >= off) x += y;
  }
  __shared__ int ws[4];
  if (lane == 63) ws[wv] = x;
  __syncthreads();
  int woff = 0;
  #pragma unroll
  for (int k = 0; k < 4; k++) if (k < wv) woff += ws[k];
  int base = bsum[b] + woff + (x - s);
  if (i0 < n)     seg[i0]     = base;
  if (i0+1 < n)   seg[i0+1]   = base + v.x;
  if (i0+2 < n)   seg[i0+2]   = base + v.x + v.y;
  if (i0+3 < n)   seg[i0+3]   = base + v.x + v.y + v.z;
}

// scatter: 12B {src, dst, eid} per edge to sorted position
__global__ void k_scatter(const int* __restrict__ src, const int* __restrict__ dst,
                          const int* __restrict__ seg, int* __restrict__ cur,
                          int* __restrict__ ssrc, int* __restrict__ sdst,
                          int* __restrict__ seid, int E){
  int e = blockIdx.x * blockDim.x + threadIdx.x;
  if (e >= E) return;
  int d = dst[e];
  int pos = seg[d] + atomicAdd(&cur[d], 1);
  ssrc[pos] = src[e];
  sdst[pos] = d;
  seid[pos] = e;
}

// ---------- W prep: transpose + bf16 hi/lo split ----------
__global__ __launch_bounds__(256) void k_prepw(
    const float* __restrict__ W0, const float* __restrict__ W1, const float* __restrict__ W2,
    const float* __restrict__ W3, const float* __restrict__ W4, const float* __restrict__ W5,
    u16* __restrict__ WtH, u16* __restrict__ WtL)
{
  int mat = blockIdx.z;
  const float* W = (mat == 0) ? W0 : (mat == 1) ? W1 : (mat == 2) ? W2 :
                   (mat == 3) ? W3 : (mat == 4) ? W4 : W5;
  __shared__ float tile[32][33];
  int kt = blockIdx.x * 32, ct = blockIdx.y * 32;
  int tr = threadIdx.x & 31, ti = threadIdx.x >> 5;
  #pragma unroll
  for (int j = 0; j < 4; j++){
    int kk = ti + 8 * j;
    tile[kk][tr] = W[(size_t)(kt + kk) * 128 + ct + tr];
  }
  __syncthreads();
  #pragma unroll
  for (int j = 0; j < 4; j++){
    int cc = ti + 8 * j;
    float v = tile[tr][cc];
    u16 hi = f2b(v);
    u16 lo = f2b(v - b2f(hi));
    size_t o = (size_t)mat * 16384 + (size_t)(ct + cc) * 128 + kt + tr;
    WtH[o] = hi;
    WtL[o] = lo;
  }
}

// ---------- node transform via MFMA (bf16x3 split) ----------
__global__ __launch_bounds__(256) void k_gemm2(
    const float* __restrict__ A,
    const u16* __restrict__ WtH, const u16* __restrict__ WtL,
    u16* __restrict__ xlb, u16* __restrict__ xrb, int nrows)
{
  __shared__ u16 sAH[64][72], sAL[64][72];
  __shared__ u16 sWH[128][72], sWL[128][72];
  int t = threadIdx.x, wv = t >> 6, lane = t & 63;
  int col = lane & 15, kg = lane >> 4;
  int r0 = blockIdx.x * 64;
  int mat = blockIdx.y;
  const u16* WHb = WtH + (size_t)mat * 16384;
  const u16* WLb = WtL + (size_t)mat * 16384;

  f32x4 acc[4][2];
  #pragma unroll
  for (int m = 0; m < 4; m++)
    #pragma unroll
    for (int n = 0; n < 2; n++)
      acc[m][n] = (f32x4){0.f, 0.f, 0.f, 0.f};

  int ar = t >> 2, ak = (t & 3) << 4;
  int wc = t >> 1, wk = (t & 1) << 5;

  for (int kh = 0; kh < 2; kh++){
    __syncthreads();
    {
      int gr = r0 + ar;
      const float* ap = A + (size_t)gr * 128 + kh * 64 + ak;
      float4 va = {0,0,0,0}, vb = {0,0,0,0}, vc = {0,0,0,0}, vd = {0,0,0,0};
      if (gr < nrows){
        va = *(const float4*)ap; vb = *(const float4*)(ap + 4);
        vc = *(const float4*)(ap + 8); vd = *(const float4*)(ap + 12);
      }
      float fv[16] = { va.x, va.y, va.z, va.w, vb.x, vb.y, vb.z, vb.w,
                       vc.x, vc.y, vc.z, vc.w, vd.x, vd.y, vd.z, vd.w };
      u32 hp[8], lp[8];
      #pragma unroll
      for (int i = 0; i < 8; i++){
        u16 h0 = f2b(fv[2*i]),   h1 = f2b(fv[2*i+1]);
        u16 l0 = f2b(fv[2*i]   - b2f(h0));
        u16 l1 = f2b(fv[2*i+1] - b2f(h1));
        hp[i] = (u32)h0 | ((u32)h1 << 16);
        lp[i] = (u32)l0 | ((u32)l1 << 16);
      }
      *(uint4*)&sAH[ar][ak]     = make_uint4(hp[0], hp[1], hp[2], hp[3]);
      *(uint4*)&sAH[ar][ak + 8] = make_uint4(hp[4], hp[5], hp[6], hp[7]);
      *(uint4*)&sAL[ar][ak]     = make_uint4(lp[0], lp[1], lp[2], lp[3]);
      *(uint4*)&sAL[ar][ak + 8] = make_uint4(lp[4], lp[5], lp[6], lp[7]);
    }
    {
      const u16* gh = WHb + (size_t)wc * 128 + kh * 64 + wk;
      const u16* gl = WLb + (size_t)wc * 128 + kh * 64 + wk;
      uint4 h0 = *(const uint4*)gh, h1 = *(const uint4*)(gh + 8);
      uint4 h2 = *(const uint4*)(gh + 16), h3 = *(const uint4*)(gh + 24);
      uint4 l0 = *(const uint4*)gl, l1 = *(const uint4*)(gl + 8);
      uint4 l2 = *(const uint4*)(gl + 16), l3 = *(const uint4*)(gl + 24);
      *(uint4*)&sWH[wc][wk]      = h0; *(uint4*)&sWH[wc][wk + 8]  = h1;
      *(uint4*)&sWH[wc][wk + 16] = h2; *(uint4*)&sWH[wc][wk + 24] = h3;
      *(uint4*)&sWL[wc][wk]      = l0; *(uint4*)&sWL[wc][wk + 8]  = l1;
      *(uint4*)&sWL[wc][wk + 16] = l2; *(uint4*)&sWL[wc][wk + 24] = l3;
    }
    __syncthreads();
    #pragma unroll
    for (int ks = 0; ks < 2; ks++){
      bf16x8 bhi0 = *(const bf16x8*)&sWH[wv*32 + col]     [ks*32 + kg*8];
      bf16x8 bhi1 = *(const bf16x8*)&sWH[wv*32 + 16 + col][ks*32 + kg*8];
      bf16x8 blo0 = *(const bf16x8*)&sWL[wv*32 + col]     [ks*32 + kg*8];
      bf16x8 blo1 = *(const bf16x8*)&sWL[wv*32 + 16 + col][ks*32 + kg*8];
      #pragma unroll
      for (int m = 0; m < 4; m++){
        bf16x8 ahv = *(const bf16x8*)&sAH[m*16 + col][ks*32 + kg*8];
        bf16x8 alv = *(const bf16x8*)&sAL[m*16 + col][ks*32 + kg*8];
        acc[m][0] = __builtin_amdgcn_mfma_f32_16x16x32_bf16(ahv, bhi0, acc[m][0], 0, 0, 0);
        acc[m][0] = __builtin_amdgcn_mfma_f32_16x16x32_bf16(alv, bhi0, acc[m][0], 0, 0, 0);
        acc[m][0] = __builtin_amdgcn_mfma_f32_16x16x32_bf16(ahv, blo0, acc[m][0], 0, 0, 0);
        acc[m][1] = __builtin_amdgcn_mfma_f32_16x16x32_bf16(ahv, bhi1, acc[m][1], 0, 0, 0);
        acc[m][1] = __builtin_amdgcn_mfma_f32_16x16x32_bf16(alv, bhi1, acc[m][1], 0, 0, 0);
        acc[m][1] = __builtin_amdgcn_mfma_f32_16x16x32_bf16(ahv, blo1, acc[m][1], 0, 0, 0);
      }
    }
  }
  u16* ob = mat ? xrb : xlb;
  #pragma unroll
  for (int m = 0; m < 4; m++){
    #pragma unroll
    for (int n = 0; n < 2; n++){
      #pragma unroll
      for (int r = 0; r < 4; r++){
        int row = r0 + m*16 + kg*4 + r;
        int c   = wv*32 + n*16 + col;
        if (row < nrows) ob[(size_t)row * 128 + c] = f2b(acc[m][n][r]);
      }
    }
  }
}

// ---------- edge kernel: swapped-operand MFMA -> per-edge channels in REGISTERS ----------
// mfma(bw_c, a): D col = edge slot (lane&15), row = channel c*16 + kg*4 + r.
// Lane (col,kg) handles edge e0+col, channels {c*16+kg*4..+3}; head sums reduced over kg.
__global__ __launch_bounds__(256) void k_edge(
    const int* __restrict__ ssrc, const int* __restrict__ sdst, const int* __restrict__ seid,
    const u16* __restrict__ ea2,
    const u16* __restrict__ xlb, const u16* __restrict__ xrb,
    const float* __restrict__ We, const float* __restrict__ att,
    float2* __restrict__ pr2, int ntiles, int E)
{
  int wv = threadIdx.x >> 6, lane = threadIdx.x & 63;
  int col = lane & 15, kg = lane >> 4;

  // We fragments (A-operand after swap): bwC[j] = We[kg*8+j][C*16+col]
#define LDWE(C) bf16x8 bw##C; { \
    _Pragma("unroll") \
    for (int j = 0; j < 8; j++) bw##C[j] = (short)f2b(We[(kg * 8 + j) * 128 + C * 16 + col]); }
  LDWE(0) LDWE(1) LDWE(2) LDWE(3) LDWE(4) LDWE(5) LDWE(6) LDWE(7)
#undef LDWE
  // att packed: channels C*16+kg*4 + {0,1} and {2,3}
#define LDAT(C) \
  u32 al##C = (u32)f2b(att[C*16 + kg*4])     | ((u32)f2b(att[C*16 + kg*4 + 1]) << 16); \
  u32 ah##C = (u32)f2b(att[C*16 + kg*4 + 2]) | ((u32)f2b(att[C*16 + kg*4 + 3]) << 16);
  LDAT(0) LDAT(1) LDAT(2) LDAT(3) LDAT(4) LDAT(5) LDAT(6) LDAT(7)
#undef LDAT

  int nw = gridDim.x * 4;
  int t = blockIdx.x * 4 + wv;
  if (t >= ntiles) return;

  // prologue: tile t loads
  int e0 = t * 16;
  int eidv = seid[e0 + col];
  int sn = ssrc[e0 + col], dn = sdst[e0 + col];
  bf16x8 a = *(const bf16x8*)(ea2 + (size_t)eidv * 32 + kg * 8);
  const u16* xjp = xlb + (size_t)sn * 128 + kg * 4;
  const u16* xip = xrb + (size_t)dn * 128 + kg * 4;
#define LDX(C, P, V) uint2 V = *(const uint2*)((P) + (C) * 16);
  LDX(0, xjp, J0) LDX(1, xjp, J1) LDX(2, xjp, J2) LDX(3, xjp, J3)
  LDX(4, xjp, J4) LDX(5, xjp, J5) LDX(6, xjp, J6) LDX(7, xjp, J7)
  LDX(0, xip, I0) LDX(1, xip, I1) LDX(2, xip, I2) LDX(3, xip, I3)
  LDX(4, xip, I4) LDX(5, xip, I5) LDX(6, xip, I6) LDX(7, xip, I7)

  while (true){
    int t2 = t + nw;
    bool more = (t2 < ntiles);
    int tc = more ? t2 : t;
    int e02 = tc * 16;
    int eid2 = seid[e02 + col];
    int sn2 = ssrc[e02 + col], dn2 = sdst[e02 + col];
    bf16x8 a2 = *(const bf16x8*)(ea2 + (size_t)eid2 * 32 + kg * 8);
    const u16* xj2 = xlb + (size_t)sn2 * 128 + kg * 4;
    const u16* xi2 = xrb + (size_t)dn2 * 128 + kg * 4;
    LDX(0, xj2, nJ0) LDX(1, xj2, nJ1) LDX(2, xj2, nJ2) LDX(3, xj2, nJ3)
    LDX(4, xj2, nJ4) LDX(5, xj2, nJ5) LDX(6, xj2, nJ6) LDX(7, xj2, nJ7)
    LDX(0, xi2, nI0) LDX(1, xi2, nI1) LDX(2, xi2, nI2) LDX(3, xi2, nI3)
    LDX(4, xi2, nI4) LDX(5, xi2, nI5) LDX(6, xi2, nI6) LDX(7, xi2, nI7)

    // MFMAs (swapped operands) -> channels in registers
    f32x4 d0 = __builtin_amdgcn_mfma_f32_16x16x32_bf16(bw0, a, (f32x4){0.f,0.f,0.f,0.f}, 0, 0, 0);
    f32x4 d1 = __builtin_amdgcn_mfma_f32_16x16x32_bf16(bw1, a, (f32x4){0.f,0.f,0.f,0.f}, 0, 0, 0);
    f32x4 d2 = __builtin_amdgcn_mfma_f32_16x16x32_bf16(bw2, a, (f32x4){0.f,0.f,0.f,0.f}, 0, 0, 0);
    f32x4 d3 = __builtin_amdgcn_mfma_f32_16x16x32_bf16(bw3, a, (f32x4){0.f,0.f,0.f,0.f}, 0, 0, 0);
    f32x4 d4 = __builtin_amdgcn_mfma_f32_16x16x32_bf16(bw4, a, (f32x4){0.f,0.f,0.f,0.f}, 0, 0, 0);
    f32x4 d5 = __builtin_amdgcn_mfma_f32_16x16x32_bf16(bw5, a, (f32x4){0.f,0.f,0.f,0.f}, 0, 0, 0);
    f32x4 d6 = __builtin_amdgcn_mfma_f32_16x16x32_bf16(bw6, a, (f32x4){0.f,0.f,0.f,0.f}, 0, 0, 0);
    f32x4 d7 = __builtin_amdgcn_mfma_f32_16x16x32_bf16(bw7, a, (f32x4){0.f,0.f,0.f,0.f}, 0, 0, 0);

    float h0 = 0.f, h1 = 0.f;
#define EPC(D, J, I, AL, AH, ACC) { \
    float v0 = D[0] + bl(J.x) + bl(I.x); v0 = fmaxf(v0, 0.2f*v0); ACC = fmaf(v0, bl(AL), ACC); \
    float v1 = D[1] + bh(J.x) + bh(I.x); v1 = fmaxf(v1, 0.2f*v1); ACC = fmaf(v1, bh(AL), ACC); \
    float v2 = D[2] + bl(J.y) + bl(I.y); v2 = fmaxf(v2, 0.2f*v2); ACC = fmaf(v2, bl(AH), ACC); \
    float v3 = D[3] + bh(J.y) + bh(I.y); v3 = fmaxf(v3, 0.2f*v3); ACC = fmaf(v3, bh(AH), ACC); }
    EPC(d0, J0, I0, al0, ah0, h0) EPC(d1, J1, I1, al1, ah1, h0)
    EPC(d2, J2, I2, al2, ah2, h0) EPC(d3, J3, I3, al3, ah3, h0)
    EPC(d4, J4, I4, al4, ah4, h1) EPC(d5, J5, I5, al5, ah5, h1)
    EPC(d6, J6, I6, al6, ah6, h1) EPC(d7, J7, I7, al7, ah7, h1)
#undef EPC

    h0 += __shfl_xor(h0, 16); h0 += __shfl_xor(h0, 32);
    h1 += __shfl_xor(h1, 16); h1 += __shfl_xor(h1, 32);
    if (kg == 0 && e0 + col < E){
      pr2[e0 + col] = make_float2(__expf(fminf(h0, 80.f)), __expf(fminf(h1, 80.f)));
    }
    if (!more) break;
    t = t2; e0 = e02; a = a2;
    J0 = nJ0; J1 = nJ1; J2 = nJ2; J3 = nJ3; J4 = nJ4; J5 = nJ5; J6 = nJ6; J7 = nJ7;
    I0 = nI0; I1 = nI1; I2 = nI2; I3 = nI3; I4 = nI4; I5 = nI5; I6 = nI6; I7 = nI7;
  }
#undef LDX
}

// ---------- per-node reduce: 8-wide named-scalar batches, 2-deep pipeline ----------
template<int RELU>
__global__ __launch_bounds__(256) void k_seg2(
    const int* __restrict__ seg, const int* __restrict__ ssrc,
    const float2* __restrict__ pr2,
    const u16* __restrict__ xlb, const float* __restrict__ bias,
    float* __restrict__ out, int N)
{
  int wid  = blockIdx.x * 4 + (threadIdx.x >> 6);
  int lane = threadIdx.x & 63;
  if (wid >= N) return;
  int c0 = lane * 2, head = lane >> 5;

  int p0 = seg[wid], p1 = seg[wid + 1];
  float2 bv = *(const float2*)(bias + c0);
  float s = 0.f, o0 = 0.f, o1 = 0.f;

  if (p0 < p1){
#define LDB(K, PP, QN, XN) \
    { int ii = (PP + K < p1) ? (PP + K) : (p1 - 1); \
      int ss = ssrc[ii]; \
      QN = pr2[ii]; \
      XN = *(const u32*)(xlb + (size_t)ss * 128 + c0); }
    float2 qa0, qa1, qa2, qa3, qa4, qa5, qa6, qa7;
    u32 xa0, xa1, xa2, xa3, xa4, xa5, xa6, xa7;
    LDB(0, p0, qa0, xa0) LDB(1, p0, qa1, xa1) LDB(2, p0, qa2, xa2) LDB(3, p0, qa3, xa3)
    LDB(4, p0, qa4, xa4) LDB(5, p0, qa5, xa5) LDB(6, p0, qa6, xa6) LDB(7, p0, qa7, xa7)
    int p = p0;
    while (true){
      int pn = p + 8;
      bool more = pn < p1;
      int pc = more ? pn : p;
      float2 qb0, qb1, qb2, qb3, qb4, qb5, qb6, qb7;
      u32 xb0, xb1, xb2, xb3, xb4, xb5, xb6, xb7;
      LDB(0, pc, qb0, xb0) LDB(1, pc, qb1, xb1) LDB(2, pc, qb2, xb2) LDB(3, pc, qb3, xb3)
      LDB(4, pc, qb4, xb4) LDB(5, pc, qb5, xb5) LDB(6, pc, qb6, xb6) LDB(7, pc, qb7, xb7)
#define ACC(K, QN, XN) { \
      float e = head ? QN.y : QN.x; \
      if (p + K >= p1) e = 0.f; \
      s += e; \
      o0 = fmaf(e, bl(XN), o0); \
      o1 = fmaf(e, bh(XN), o1); }
      ACC(0, qa0, xa0) ACC(1, qa1, xa1) ACC(2, qa2, xa2) ACC(3, qa3, xa3)
      ACC(4, qa4, xa4) ACC(5, qa5, xa5) ACC(6, qa6, xa6) ACC(7, qa7, xa7)
#undef ACC
      if (!more) break;
      p = pn;
      qa0 = qb0; xa0 = xb0; qa1 = qb1; xa1 = xb1;
      qa2 = qb2; xa2 = xb2; qa3 = qb3; xa3 = xb3;
      qa4 = qb4; xa4 = xb4; qa5 = qb5; xa5 = xb5;
      qa6 = qb6; xa6 = xb6; qa7 = qb7; xa7 = xb7;
    }
#undef LDB
  }
  float inv = 1.0f / (s + 1e-16f);
  float r0 = fmaf(o0, inv, bv.x);
  float r1 = fmaf(o1, inv, bv.y);
  if (RELU){ r0 = fmaxf(r0, 0.f); r1 = fmaxf(r1, 0.f); }
  *(float2*)(out + (size_t)wid * 128 + c0) = make_float2(r0, r1);
}

// ---------- launch ----------
extern "C" void kernel_launch(void* const* d_in, const int* in_sizes, int n_in,
                              void* d_out, int out_size, void* d_ws, size_t ws_size,
                              hipStream_t stream)
{
  const float* x     = (const float*)d_in[0];
  const int*   ei    = (const int*)  d_in[1];
  const float* eattr = (const float*)d_in[2];
  const float* Wp[3][5];
  for (int l = 0; l < 3; l++)
    for (int j = 0; j < 5; j++)
      Wp[l][j] = (const float*)d_in[3 + l * 5 + j];

  int N = in_sizes[0] / 128;
  int E = in_sizes[2] / 32;

  char* w = (char*)d_ws;
  auto alloc = [&](size_t bytes) -> char* {
    char* p = w; w += (bytes + 255) & ~(size_t)255; return p;
  };
  float* xr   = (float*)alloc((size_t)N * 128 * 4);   // inter-layer h buffer
  u16*   xlb  = (u16*)  alloc((size_t)N * 128 * 2);
  u16*   xrb  = (u16*)  alloc((size_t)N * 128 * 2);
  u16*   ea2  = (u16*)  alloc((size_t)(E + 64) * 32 * 2);
  float2* prb = (float2*)alloc((size_t)E * 8);
  u16*   WtH  = (u16*)  alloc((size_t)6 * 16384 * 2);
  u16*   WtL  = (u16*)  alloc((size_t)6 * 16384 * 2);
  int* srcA   = (int*)alloc((size_t)E * 4);
  int* dstA   = (int*)alloc((size_t)E * 4);
  int* ssrc   = (int*)alloc((size_t)(E + 64) * 4);
  int* sdst   = (int*)alloc((size_t)(E + 64) * 4);
  int* seid   = (int*)alloc((size_t)(E + 64) * 4);
  int* deg    = (int*)alloc((size_t)N * 4);
  int* cur    = (int*)alloc((size_t)N * 4);
  int* seg    = (int*)alloc((size_t)(N + 1) * 4);
  int* bsum   = (int*)alloc(1024 * 4);
  u32* flag   = (u32*)alloc(256);

  hipMemsetAsync(deg,  0, (size_t)N * 4, stream);
  hipMemsetAsync(cur,  0, (size_t)N * 4, stream);
  hipMemsetAsync(flag, 0, 4, stream);
  hipMemsetAsync(ssrc + E, 0, 64 * 4, stream);   // pads: valid node/edge index 0
  hipMemsetAsync(sdst + E, 0, 64 * 4, stream);
  hipMemsetAsync(seid + E, 0, 64 * 4, stream);

  int ndet = (E < 16384) ? E : 16384;
  k_detect<<<(ndet + 255) / 256, 256, 0, stream>>>((const u32*)ei, ndet, flag);
  int gE = (E + 255) / 256;
  k_convhist<<<gE, 256, 0, stream>>>(ei, srcA, dstA, deg, eattr, ea2, E, flag);
  int nb = (N + 1023) / 1024;
  k_scan1<<<nb, 256, 0, stream>>>(deg, bsum, N);
  k_scan2<<<1, 1024, 0, stream>>>(bsum, nb, seg + N);
  k_scan3<<<nb, 256, 0, stream>>>(deg, bsum, seg, N);
  k_scatter<<<gE, 256, 0, stream>>>(srcA, dstA, seg, cur, ssrc, sdst, seid, E);
  dim3 gp(4, 4, 6);
  k_prepw<<<gp, 256, 0, stream>>>(Wp[0][0], Wp[0][1], Wp[1][0], Wp[1][1], Wp[2][0], Wp[2][1], WtH, WtL);

  int gS = (N + 3) / 4;
  int ntiles = (E + 15) / 16;
  int gEdge = (ntiles + 3) / 4; if (gEdge > 2048) gEdge = 2048;
  dim3 gG2((N + 63) / 64, 2);

  const float* hin = x;
  for (int l = 0; l < 3; l++){
    k_gemm2<<<gG2, 256, 0, stream>>>(hin, WtH + (size_t)l * 2 * 16384, WtL + (size_t)l * 2 * 16384, xlb, xrb, N);
    k_edge<<<gEdge, 256, 0, stream>>>(ssrc, sdst, seid, ea2, xlb, xrb, Wp[l][2], Wp[l][3], prb, ntiles, E);
    float* outp = (l == 2) ? (float*)d_out : xr;
    if (l == 2) k_seg2<0><<<gS, 256, 0, stream>>>(seg, ssrc, prb, xlb, Wp[l][4], outp, N);
    else        k_seg2<1><<<gS, 256, 0, stream>>>(seg, ssrc, prb, xlb, Wp[l][4], outp, N);
    hin = xr;
  }
}

// Round 14
// 547.738 us; speedup vs baseline: 1.0923x; 1.0923x over previous
//
#include <hip/hip_runtime.h>

typedef unsigned int u32;
typedef unsigned short u16;
typedef __attribute__((ext_vector_type(8))) short bf16x8;
typedef __attribute__((ext_vector_type(4))) float f32x4;

__device__ __forceinline__ u16 f2b(float f){
  u32 x = __float_as_uint(f);
  u32 r = (x + 0x7fffu + ((x >> 16) & 1u)) >> 16;
  return (u16)r;
}
__device__ __forceinline__ float b2f(u16 h){ return __uint_as_float((u32)h << 16); }
__device__ __forceinline__ float bl(u32 u){ return __uint_as_float(u << 16); }
__device__ __forceinline__ float bh(u32 u){ return __uint_as_float(u & 0xffff0000u); }

// ---------- preprocessing ----------

__global__ void k_detect(const u32* __restrict__ ei, int n, u32* __restrict__ flag){
  int t = blockIdx.x * blockDim.x + threadIdx.x;
  u32 v = 0;
  if (t < n) v = ei[2 * t + 1];
  unsigned long long b = __ballot(v != 0u);
  if ((threadIdx.x & 63) == 0 && b) atomicOr(flag, 1u);
}

// fused: index convert + degree histogram + eattr -> bf16 (original order, coalesced)
__global__ void k_convhist(const int* __restrict__ ei, int* __restrict__ src, int* __restrict__ dst,
                           int* __restrict__ deg, const float* __restrict__ eattr,
                           u16* __restrict__ ea2, int E, const u32* __restrict__ flag){
  int e = blockIdx.x * blockDim.x + threadIdx.x;
  if (e >= E) return;
  bool is64 = (*flag == 0u);
  int s, d;
  if (is64){ s = ei[2 * e]; d = ei[2 * (E + e)]; }
  else     { s = ei[e];     d = ei[E + e]; }
  src[e] = s; dst[e] = d;
  atomicAdd(&deg[d], 1);
  const float4* srow = (const float4*)(eattr + (size_t)e * 32);
  u32 pk[16];
  #pragma unroll
  for (int i = 0; i < 8; i++){
    float4 v = srow[i];
    pk[2*i]   = (u32)f2b(v.x) | ((u32)f2b(v.y) << 16);
    pk[2*i+1] = (u32)f2b(v.z) | ((u32)f2b(v.w) << 16);
  }
  uint4* drow = (uint4*)(ea2 + (size_t)e * 32);
  drow[0] = make_uint4(pk[0], pk[1], pk[2], pk[3]);
  drow[1] = make_uint4(pk[4], pk[5], pk[6], pk[7]);
  drow[2] = make_uint4(pk[8], pk[9], pk[10], pk[11]);
  drow[3] = make_uint4(pk[12], pk[13], pk[14], pk[15]);
}

// hierarchical scan
__global__ __launch_bounds__(256) void k_scan1(const int* __restrict__ deg, int* __restrict__ bsum, int n){
  int b = blockIdx.x, t = threadIdx.x, lane = t & 63, wv = t >> 6;
  int i0 = b * 1024 + t * 4;
  int4 v = make_int4(0,0,0,0);
  if (i0 + 3 < n) v = *(const int4*)(deg + i0);
  else { if (i0 < n) v.x = deg[i0]; if (i0+1 < n) v.y = deg[i0+1]; if (i0+2 < n) v.z = deg[i0+2]; }
  int s = v.x + v.y + v.z + v.w;
  #pragma unroll
  for (int off = 1; off < 64; off <<= 1) s += __shfl_xor(s, off);
  __shared__ int ws[4];
  if (lane == 0) ws[wv] = s;
  __syncthreads();
  if (t == 0) bsum[b] = ws[0] + ws[1] + ws[2] + ws[3];
}

__global__ __launch_bounds__(1024) void k_scan2(int* __restrict__ bsum, int nb, int* __restrict__ segN){
  int t = threadIdx.x, lane = t & 63, w = t >> 6;
  int v = (t < nb) ? bsum[t] : 0;
  int x = v;
  #pragma unroll
  for (int off = 1; off < 64; off <<= 1){
    int y = __shfl_up(x, off);
    if (lane >= off) x += y;
  }
  __shared__ int wsum[16];
  if (lane == 63) wsum[w] = x;
  __syncthreads();
  if (w == 0 && lane < 16){
    int sv = wsum[lane];
    #pragma unroll
    for (int off = 1; off < 16; off <<= 1){
      int y = __shfl_up(sv, off);
      if (lane >= off) sv += y;
    }
    wsum[lane] = sv;
  }
  __syncthreads();
  int woff = (w > 0) ? wsum[w - 1] : 0;
  if (t < nb) bsum[t] = woff + x - v;
  if (t == 0) *segN = wsum[15];
}

__global__ __launch_bounds__(256) void k_scan3(const int* __restrict__ deg, const int* __restrict__ bsum,
                                               int* __restrict__ seg, int n){
  int b = blockIdx.x, t = threadIdx.x, lane = t & 63, wv = t >> 6;
  int i0 = b * 1024 + t * 4;
  int4 v = make_int4(0,0,0,0);
  if (i0 + 3 < n) v = *(const int4*)(deg + i0);
  else { if (i0 < n) v.x = deg[i0]; if (i0+1 < n) v.y = deg[i0+1]; if (i0+2 < n) v.z = deg[i0+2]; }
  int s = v.x + v.y + v.z + v.w;
  int x = s;
  #pragma unroll
  for (int off = 1; off < 64; off <<= 1){
    int y = __shfl_up(x, off);
    if (lane >= off) x += y;
  }
  __shared__ int ws[4];
  if (lane == 63) ws[wv] = x;
  __syncthreads();
  int woff = 0;
  #pragma unroll
  for (int k = 0; k < 4; k++) if (k < wv) woff += ws[k];
  int base = bsum[b] + woff + (x - s);
  if (i0 < n)     seg[i0]     = base;
  if (i0+1 < n)   seg[i0+1]   = base + v.x;
  if (i0+2 < n)   seg[i0+2]   = base + v.x + v.y;
  if (i0+3 < n)   seg[i0+3]   = base + v.x + v.y + v.z;
}

// scatter: 12B {src, dst, eid} per edge to sorted position
__global__ void k_scatter(const int* __restrict__ src, const int* __restrict__ dst,
                          const int* __restrict__ seg, int* __restrict__ cur,
                          int* __restrict__ ssrc, int* __restrict__ sdst,
                          int* __restrict__ seid, int E){
  int e = blockIdx.x * blockDim.x + threadIdx.x;
  if (e >= E) return;
  int d = dst[e];
  int pos = seg[d] + atomicAdd(&cur[d], 1);
  ssrc[pos] = src[e];
  sdst[pos] = d;
  seid[pos] = e;
}

// sort bf16 ea2 into dst-sorted order: random 64B row reads, coalesced writes
__global__ void k_sortb(const int* __restrict__ seid, const u16* __restrict__ ea2o,
                        u16* __restrict__ ea2s, int E){
  int t = blockIdx.x * blockDim.x + threadIdx.x;
  int e = t >> 2, j = t & 3;
  if (e >= E) return;
  int eid = seid[e];
  uint4 v = *(const uint4*)(ea2o + (size_t)eid * 32 + j * 8);
  *(uint4*)(ea2s + (size_t)e * 32 + j * 8) = v;
}

// ---------- W prep: transpose + bf16 hi/lo split ----------
__global__ __launch_bounds__(256) void k_prepw(
    const float* __restrict__ W0, const float* __restrict__ W1, const float* __restrict__ W2,
    const float* __restrict__ W3, const float* __restrict__ W4, const float* __restrict__ W5,
    u16* __restrict__ WtH, u16* __restrict__ WtL)
{
  int mat = blockIdx.z;
  const float* W = (mat == 0) ? W0 : (mat == 1) ? W1 : (mat == 2) ? W2 :
                   (mat == 3) ? W3 : (mat == 4) ? W4 : W5;
  __shared__ float tile[32][33];
  int kt = blockIdx.x * 32, ct = blockIdx.y * 32;
  int tr = threadIdx.x & 31, ti = threadIdx.x >> 5;
  #pragma unroll
  for (int j = 0; j < 4; j++){
    int kk = ti + 8 * j;
    tile[kk][tr] = W[(size_t)(kt + kk) * 128 + ct + tr];
  }
  __syncthreads();
  #pragma unroll
  for (int j = 0; j < 4; j++){
    int cc = ti + 8 * j;
    float v = tile[tr][cc];
    u16 hi = f2b(v);
    u16 lo = f2b(v - b2f(hi));
    size_t o = (size_t)mat * 16384 + (size_t)(ct + cc) * 128 + kt + tr;
    WtH[o] = hi;
    WtL[o] = lo;
  }
}

// ---------- node transform via MFMA (bf16x3 split) ----------
__global__ __launch_bounds__(256) void k_gemm2(
    const float* __restrict__ A,
    const u16* __restrict__ WtH, const u16* __restrict__ WtL,
    u16* __restrict__ xlb, u16* __restrict__ xrb, int nrows)
{
  __shared__ u16 sAH[64][72], sAL[64][72];
  __shared__ u16 sWH[128][72], sWL[128][72];
  int t = threadIdx.x, wv = t >> 6, lane = t & 63;
  int col = lane & 15, kg = lane >> 4;
  int r0 = blockIdx.x * 64;
  int mat = blockIdx.y;
  const u16* WHb = WtH + (size_t)mat * 16384;
  const u16* WLb = WtL + (size_t)mat * 16384;

  f32x4 acc[4][2];
  #pragma unroll
  for (int m = 0; m < 4; m++)
    #pragma unroll
    for (int n = 0; n < 2; n++)
      acc[m][n] = (f32x4){0.f, 0.f, 0.f, 0.f};

  int ar = t >> 2, ak = (t & 3) << 4;
  int wc = t >> 1, wk = (t & 1) << 5;

  for (int kh = 0; kh < 2; kh++){
    __syncthreads();
    {
      int gr = r0 + ar;
      const float* ap = A + (size_t)gr * 128 + kh * 64 + ak;
      float4 va = {0,0,0,0}, vb = {0,0,0,0}, vc = {0,0,0,0}, vd = {0,0,0,0};
      if (gr < nrows){
        va = *(const float4*)ap; vb = *(const float4*)(ap + 4);
        vc = *(const float4*)(ap + 8); vd = *(const float4*)(ap + 12);
      }
      float fv[16] = { va.x, va.y, va.z, va.w, vb.x, vb.y, vb.z, vb.w,
                       vc.x, vc.y, vc.z, vc.w, vd.x, vd.y, vd.z, vd.w };
      u32 hp[8], lp[8];
      #pragma unroll
      for (int i = 0; i < 8; i++){
        u16 h0 = f2b(fv[2*i]),   h1 = f2b(fv[2*i+1]);
        u16 l0 = f2b(fv[2*i]   - b2f(h0));
        u16 l1 = f2b(fv[2*i+1] - b2f(h1));
        hp[i] = (u32)h0 | ((u32)h1 << 16);
        lp[i] = (u32)l0 | ((u32)l1 << 16);
      }
      *(uint4*)&sAH[ar][ak]     = make_uint4(hp[0], hp[1], hp[2], hp[3]);
      *(uint4*)&sAH[ar][ak + 8] = make_uint4(hp[4], hp[5], hp[6], hp[7]);
      *(uint4*)&sAL[ar][ak]     = make_uint4(lp[0], lp[1], lp[2], lp[3]);
      *(uint4*)&sAL[ar][ak + 8] = make_uint4(lp[4], lp[5], lp[6], lp[7]);
    }
    {
      const u16* gh = WHb + (size_t)wc * 128 + kh * 64 + wk;
      const u16* gl = WLb + (size_t)wc * 128 + kh * 64 + wk;
      uint4 h0 = *(const uint4*)gh, h1 = *(const uint4*)(gh + 8);
      uint4 h2 = *(const uint4*)(gh + 16), h3 = *(const uint4*)(gh + 24);
      uint4 l0 = *(const uint4*)gl, l1 = *(const uint4*)(gl + 8);
      uint4 l2 = *(const uint4*)(gl + 16), l3 = *(const uint4*)(gl + 24);
      *(uint4*)&sWH[wc][wk]      = h0; *(uint4*)&sWH[wc][wk + 8]  = h1;
      *(uint4*)&sWH[wc][wk + 16] = h2; *(uint4*)&sWH[wc][wk + 24] = h3;
      *(uint4*)&sWL[wc][wk]      = l0; *(uint4*)&sWL[wc][wk + 8]  = l1;
      *(uint4*)&sWL[wc][wk + 16] = l2; *(uint4*)&sWL[wc][wk + 24] = l3;
    }
    __syncthreads();
    #pragma unroll
    for (int ks = 0; ks < 2; ks++){
      bf16x8 bhi0 = *(const bf16x8*)&sWH[wv*32 + col]     [ks*32 + kg*8];
      bf16x8 bhi1 = *(const bf16x8*)&sWH[wv*32 + 16 + col][ks*32 + kg*8];
      bf16x8 blo0 = *(const bf16x8*)&sWL[wv*32 + col]     [ks*32 + kg*8];
      bf16x8 blo1 = *(const bf16x8*)&sWL[wv*32 + 16 + col][ks*32 + kg*8];
      #pragma unroll
      for (int m = 0; m < 4; m++){
        bf16x8 ahv = *(const bf16x8*)&sAH[m*16 + col][ks*32 + kg*8];
        bf16x8 alv = *(const bf16x8*)&sAL[m*16 + col][ks*32 + kg*8];
        acc[m][0] = __builtin_amdgcn_mfma_f32_16x16x32_bf16(ahv, bhi0, acc[m][0], 0, 0, 0);
        acc[m][0] = __builtin_amdgcn_mfma_f32_16x16x32_bf16(alv, bhi0, acc[m][0], 0, 0, 0);
        acc[m][0] = __builtin_amdgcn_mfma_f32_16x16x32_bf16(ahv, blo0, acc[m][0], 0, 0, 0);
        acc[m][1] = __builtin_amdgcn_mfma_f32_16x16x32_bf16(ahv, bhi1, acc[m][1], 0, 0, 0);
        acc[m][1] = __builtin_amdgcn_mfma_f32_16x16x32_bf16(alv, bhi1, acc[m][1], 0, 0, 0);
        acc[m][1] = __builtin_amdgcn_mfma_f32_16x16x32_bf16(ahv, blo1, acc[m][1], 0, 0, 0);
      }
    }
  }
  u16* ob = mat ? xrb : xlb;
  #pragma unroll
  for (int m = 0; m < 4; m++){
    #pragma unroll
    for (int n = 0; n < 2; n++){
      #pragma unroll
      for (int r = 0; r < 4; r++){
        int row = r0 + m*16 + kg*4 + r;
        int c   = wv*32 + n*16 + col;
        if (row < nrows) ob[(size_t)row * 128 + c] = f2b(acc[m][n][r]);
      }
    }
  }
}

// ---------- edge kernel: sorted streaming ea2s; MFMA + LDS bounce + 2-deep pipeline ----------
__global__ __launch_bounds__(256) void k_edge(
    const int* __restrict__ ssrc, const int* __restrict__ sdst,
    const u16* __restrict__ ea2s,
    const u16* __restrict__ xlb, const u16* __restrict__ xrb,
    const float* __restrict__ We, const float* __restrict__ att,
    float2* __restrict__ pr2, int ntiles, int E)
{
  __shared__ float sD[4][16][132];
  int wv = threadIdx.x >> 6, lane = threadIdx.x & 63;
  int col = lane & 15, kg = lane >> 4;
  int er = lane >> 2, q = lane & 3;

  bf16x8 bw[8];
  #pragma unroll
  for (int c = 0; c < 8; c++)
    #pragma unroll
    for (int j = 0; j < 8; j++)
      bw[c][j] = (short)f2b(We[(kg * 8 + j) * 128 + c * 16 + col]);
  u32 attp[16];
  #pragma unroll
  for (int i = 0; i < 16; i++)
    attp[i] = (u32)f2b(att[q * 32 + 2*i]) | ((u32)f2b(att[q * 32 + 2*i + 1]) << 16);

  int nw = gridDim.x * 4;
  int t = blockIdx.x * 4 + wv;
  if (t >= ntiles) return;

  // prologue: tile t loads (ea2s streamed: tile rows are contiguous)
  int e0 = t * 16;
  bf16x8 a = *(const bf16x8*)(ea2s + (size_t)(e0 + col) * 32 + kg * 8);
  int p = e0 + er;
  int sn = ssrc[p], dn = sdst[p];
  const u16* xjp = xlb + (size_t)sn * 128 + q * 32;
  const u16* xip = xrb + (size_t)dn * 128 + q * 32;
  uint4 j0 = ((const uint4*)xjp)[0], j1 = ((const uint4*)xjp)[1],
        j2 = ((const uint4*)xjp)[2], j3 = ((const uint4*)xjp)[3];
  uint4 i0 = ((const uint4*)xip)[0], i1 = ((const uint4*)xip)[1],
        i2 = ((const uint4*)xip)[2], i3 = ((const uint4*)xip)[3];

  while (true){
    int t2 = t + nw;
    bool more = (t2 < ntiles);
    int tc = more ? t2 : t;
    int e02 = tc * 16;
    int p2 = e02 + er;
    int sn2 = ssrc[p2], dn2 = sdst[p2];
    bf16x8 a2 = *(const bf16x8*)(ea2s + (size_t)(e02 + col) * 32 + kg * 8);

    // MFMA current tile -> LDS
    #pragma unroll
    for (int c = 0; c < 8; c++){
      f32x4 d = __builtin_amdgcn_mfma_f32_16x16x32_bf16(a, bw[c], (f32x4){0.f,0.f,0.f,0.f}, 0, 0, 0);
      #pragma unroll
      for (int r = 0; r < 4; r++)
        sD[wv][kg * 4 + r][c * 16 + col] = d[r];
    }

    // issue next-tile gathers
    const u16* xj2 = xlb + (size_t)sn2 * 128 + q * 32;
    const u16* xi2 = xrb + (size_t)dn2 * 128 + q * 32;
    uint4 nj0 = ((const uint4*)xj2)[0], nj1 = ((const uint4*)xj2)[1],
          nj2 = ((const uint4*)xj2)[2], nj3 = ((const uint4*)xj2)[3];
    uint4 ni0 = ((const uint4*)xi2)[0], ni1 = ((const uint4*)xi2)[1],
          ni2 = ((const uint4*)xi2)[2], ni3 = ((const uint4*)xi2)[3];

    // epilogue current tile
    const float* drow = &sD[wv][er][q * 32];
    float acc = 0.f;
#define EPK(KO, JQ, IQ) { \
    float4 d0 = *(const float4*)(drow + KO*8); \
    float4 d1 = *(const float4*)(drow + KO*8 + 4); \
    float v; u32 jw, iw, aw; \
    jw = JQ.x; iw = IQ.x; aw = attp[KO*4+0]; \
    v = d0.x + bl(jw) + bl(iw); v = fmaxf(v, 0.2f*v); acc = fmaf(v, bl(aw), acc); \
    v = d0.y + bh(jw) + bh(iw); v = fmaxf(v, 0.2f*v); acc = fmaf(v, bh(aw), acc); \
    jw = JQ.y; iw = IQ.y; aw = attp[KO*4+1]; \
    v = d0.z + bl(jw) + bl(iw); v = fmaxf(v, 0.2f*v); acc = fmaf(v, bl(aw), acc); \
    v = d0.w + bh(jw) + bh(iw); v = fmaxf(v, 0.2f*v); acc = fmaf(v, bh(aw), acc); \
    jw = JQ.z; iw = IQ.z; aw = attp[KO*4+2]; \
    v = d1.x + bl(jw) + bl(iw); v = fmaxf(v, 0.2f*v); acc = fmaf(v, bl(aw), acc); \
    v = d1.y + bh(jw) + bh(iw); v = fmaxf(v, 0.2f*v); acc = fmaf(v, bh(aw), acc); \
    jw = JQ.w; iw = IQ.w; aw = attp[KO*4+3]; \
    v = d1.z + bl(jw) + bl(iw); v = fmaxf(v, 0.2f*v); acc = fmaf(v, bl(aw), acc); \
    v = d1.w + bh(jw) + bh(iw); v = fmaxf(v, 0.2f*v); acc = fmaf(v, bh(aw), acc); }
    EPK(0, j0, i0) EPK(1, j1, i1) EPK(2, j2, i2) EPK(3, j3, i3)
#undef EPK
    acc += __shfl_xor(acc, 1);
    float other = __shfl_xor(acc, 2);
    if (q == 0 && p < E){
      pr2[p] = make_float2(__expf(fminf(acc, 80.f)), __expf(fminf(other, 80.f)));
    }
    if (!more) break;
    t = t2; p = p2; a = a2;
    j0 = nj0; j1 = nj1; j2 = nj2; j3 = nj3;
    i0 = ni0; i1 = ni1; i2 = ni2; i3 = ni3;
  }
}

// ---------- per-node reduce: 8-wide named-scalar batches, 2-deep pipeline ----------
template<int RELU>
__global__ __launch_bounds__(256) void k_seg2(
    const int* __restrict__ seg, const int* __restrict__ ssrc,
    const float2* __restrict__ pr2,
    const u16* __restrict__ xlb, const float* __restrict__ bias,
    float* __restrict__ out, int N)
{
  int wid  = blockIdx.x * 4 + (threadIdx.x >> 6);
  int lane = threadIdx.x & 63;
  if (wid >= N) return;
  int c0 = lane * 2, head = lane >> 5;

  int p0 = seg[wid], p1 = seg[wid + 1];
  float2 bv = *(const float2*)(bias + c0);
  float s = 0.f, o0 = 0.f, o1 = 0.f;

  if (p0 < p1){
#define LDB(K, PP, QN, XN) \
    { int ii = (PP + K < p1) ? (PP + K) : (p1 - 1); \
      int ss = ssrc[ii]; \
      QN = pr2[ii]; \
      XN = *(const u32*)(xlb + (size_t)ss * 128 + c0); }
    float2 qa0, qa1, qa2, qa3, qa4, qa5, qa6, qa7;
    u32 xa0, xa1, xa2, xa3, xa4, xa5, xa6, xa7;
    LDB(0, p0, qa0, xa0) LDB(1, p0, qa1, xa1) LDB(2, p0, qa2, xa2) LDB(3, p0, qa3, xa3)
    LDB(4, p0, qa4, xa4) LDB(5, p0, qa5, xa5) LDB(6, p0, qa6, xa6) LDB(7, p0, qa7, xa7)
    int p = p0;
    while (true){
      int pn = p + 8;
      bool more = pn < p1;
      int pc = more ? pn : p;
      float2 qb0, qb1, qb2, qb3, qb4, qb5, qb6, qb7;
      u32 xb0, xb1, xb2, xb3, xb4, xb5, xb6, xb7;
      LDB(0, pc, qb0, xb0) LDB(1, pc, qb1, xb1) LDB(2, pc, qb2, xb2) LDB(3, pc, qb3, xb3)
      LDB(4, pc, qb4, xb4) LDB(5, pc, qb5, xb5) LDB(6, pc, qb6, xb6) LDB(7, pc, qb7, xb7)
#define ACC(K, QN, XN) { \
      float e = head ? QN.y : QN.x; \
      if (p + K >= p1) e = 0.f; \
      s += e; \
      o0 = fmaf(e, bl(XN), o0); \
      o1 = fmaf(e, bh(XN), o1); }
      ACC(0, qa0, xa0) ACC(1, qa1, xa1) ACC(2, qa2, xa2) ACC(3, qa3, xa3)
      ACC(4, qa4, xa4) ACC(5, qa5, xa5) ACC(6, qa6, xa6) ACC(7, qa7, xa7)
#undef ACC
      if (!more) break;
      p = pn;
      qa0 = qb0; xa0 = xb0; qa1 = qb1; xa1 = xb1;
      qa2 = qb2; xa2 = xb2; qa3 = qb3; xa3 = xb3;
      qa4 = qb4; xa4 = xb4; qa5 = qb5; xa5 = xb5;
      qa6 = qb6; xa6 = xb6; qa7 = qb7; xa7 = xb7;
    }
#undef LDB
  }
  float inv = 1.0f / (s + 1e-16f);
  float r0 = fmaf(o0, inv, bv.x);
  float r1 = fmaf(o1, inv, bv.y);
  if (RELU){ r0 = fmaxf(r0, 0.f); r1 = fmaxf(r1, 0.f); }
  *(float2*)(out + (size_t)wid * 128 + c0) = make_float2(r0, r1);
}

// ---------- launch ----------
extern "C" void kernel_launch(void* const* d_in, const int* in_sizes, int n_in,
                              void* d_out, int out_size, void* d_ws, size_t ws_size,
                              hipStream_t stream)
{
  const float* x     = (const float*)d_in[0];
  const int*   ei    = (const int*)  d_in[1];
  const float* eattr = (const float*)d_in[2];
  const float* Wp[3][5];
  for (int l = 0; l < 3; l++)
    for (int j = 0; j < 5; j++)
      Wp[l][j] = (const float*)d_in[3 + l * 5 + j];

  int N = in_sizes[0] / 128;
  int E = in_sizes[2] / 32;

  char* w = (char*)d_ws;
  auto alloc = [&](size_t bytes) -> char* {
    char* p = w; w += (bytes + 255) & ~(size_t)255; return p;
  };
  float* xr   = (float*)alloc((size_t)N * 128 * 4);   // inter-layer h buffer
  u16*   xlb  = (u16*)  alloc((size_t)N * 128 * 2);
  u16*   xrb  = (u16*)  alloc((size_t)N * 128 * 2);
  u16*   ea2o = (u16*)  alloc((size_t)E * 32 * 2);           // original order bf16
  u16*   ea2s = (u16*)  alloc((size_t)(E + 64) * 32 * 2);    // dst-sorted bf16
  float2* prb = (float2*)alloc((size_t)E * 8);
  u16*   WtH  = (u16*)  alloc((size_t)6 * 16384 * 2);
  u16*   WtL  = (u16*)  alloc((size_t)6 * 16384 * 2);
  int* srcA   = (int*)alloc((size_t)E * 4);
  int* dstA   = (int*)alloc((size_t)E * 4);
  int* ssrc   = (int*)alloc((size_t)(E + 64) * 4);
  int* sdst   = (int*)alloc((size_t)(E + 64) * 4);
  int* seid   = (int*)alloc((size_t)E * 4);
  int* deg    = (int*)alloc((size_t)N * 4);
  int* cur    = (int*)alloc((size_t)N * 4);
  int* seg    = (int*)alloc((size_t)(N + 1) * 4);
  int* bsum   = (int*)alloc(1024 * 4);
  u32* flag   = (u32*)alloc(256);

  hipMemsetAsync(deg,  0, (size_t)N * 4, stream);
  hipMemsetAsync(cur,  0, (size_t)N * 4, stream);
  hipMemsetAsync(flag, 0, 4, stream);
  hipMemsetAsync(ssrc + E, 0, 64 * 4, stream);   // pads: valid node index 0
  hipMemsetAsync(sdst + E, 0, 64 * 4, stream);
  hipMemsetAsync(ea2s + (size_t)E * 32, 0, 64 * 32 * 2, stream);  // pad rows: zeros

  int ndet = (E < 16384) ? E : 16384;
  k_detect<<<(ndet + 255) / 256, 256, 0, stream>>>((const u32*)ei, ndet, flag);
  int gE = (E + 255) / 256;
  k_convhist<<<gE, 256, 0, stream>>>(ei, srcA, dstA, deg, eattr, ea2o, E, flag);
  int nb = (N + 1023) / 1024;
  k_scan1<<<nb, 256, 0, stream>>>(deg, bsum, N);
  k_scan2<<<1, 1024, 0, stream>>>(bsum, nb, seg + N);
  k_scan3<<<nb, 256, 0, stream>>>(deg, bsum, seg, N);
  k_scatter<<<gE, 256, 0, stream>>>(srcA, dstA, seg, cur, ssrc, sdst, seid, E);
  k_sortb<<<(E * 4 + 255) / 256, 256, 0, stream>>>(seid, ea2o, ea2s, E);
  dim3 gp(4, 4, 6);
  k_prepw<<<gp, 256, 0, stream>>>(Wp[0][0], Wp[0][1], Wp[1][0], Wp[1][1], Wp[2][0], Wp[2][1], WtH, WtL);

  int gS = (N + 3) / 4;
  int ntiles = (E + 15) / 16;
  int gEdge = (ntiles + 3) / 4; if (gEdge > 2048) gEdge = 2048;
  dim3 gG2((N + 63) / 64, 2);

  const float* hin = x;
  for (int l = 0; l < 3; l++){
    k_gemm2<<<gG2, 256, 0, stream>>>(hin, WtH + (size_t)l * 2 * 16384, WtL + (size_t)l * 2 * 16384, xlb, xrb, N);
    k_edge<<<gEdge, 256, 0, stream>>>(ssrc, sdst, ea2s, xlb, xrb, Wp[l][2], Wp[l][3], prb, ntiles, E);
    float* outp = (l == 2) ? (float*)d_out : xr;
    if (l == 2) k_seg2<0><<<gS, 256, 0, stream>>>(seg, ssrc, prb, xlb, Wp[l][4], outp, N);
    else        k_seg2<1><<<gS, 256, 0, stream>>>(seg, ssrc, prb, xlb, Wp[l][4], outp, N);
    hin = xr;
  }
}

// Round 15
// 489.759 us; speedup vs baseline: 1.2217x; 1.1184x over previous
//
#include <hip/hip_runtime.h>

typedef unsigned int u32;
typedef unsigned short u16;
typedef __attribute__((ext_vector_type(8))) short bf16x8;
typedef __attribute__((ext_vector_type(4))) float f32x4;

__device__ __forceinline__ u16 f2b(float f){
  u32 x = __float_as_uint(f);
  u32 r = (x + 0x7fffu + ((x >> 16) & 1u)) >> 16;
  return (u16)r;
}
__device__ __forceinline__ float b2f(u16 h){ return __uint_as_float((u32)h << 16); }
__device__ __forceinline__ float bl(u32 u){ return __uint_as_float(u << 16); }
__device__ __forceinline__ float bh(u32 u){ return __uint_as_float(u & 0xffff0000u); }

// ---------- preprocessing ----------

__global__ void k_detect(const u32* __restrict__ ei, int n, u32* __restrict__ flag){
  int t = blockIdx.x * blockDim.x + threadIdx.x;
  u32 v = 0;
  if (t < n) v = ei[2 * t + 1];
  unsigned long long b = __ballot(v != 0u);
  if ((threadIdx.x & 63) == 0 && b) atomicOr(flag, 1u);
}

// fused: index convert + degree histogram + eattr -> bf16 (original order, coalesced)
__global__ void k_convhist(const int* __restrict__ ei, int* __restrict__ src, int* __restrict__ dst,
                           int* __restrict__ deg, const float* __restrict__ eattr,
                           u16* __restrict__ ea2, int E, const u32* __restrict__ flag){
  int e = blockIdx.x * blockDim.x + threadIdx.x;
  if (e >= E) return;
  bool is64 = (*flag == 0u);
  int s, d;
  if (is64){ s = ei[2 * e]; d = ei[2 * (E + e)]; }
  else     { s = ei[e];     d = ei[E + e]; }
  src[e] = s; dst[e] = d;
  atomicAdd(&deg[d], 1);
  const float4* srow = (const float4*)(eattr + (size_t)e * 32);
  u32 pk[16];
  #pragma unroll
  for (int i = 0; i < 8; i++){
    float4 v = srow[i];
    pk[2*i]   = (u32)f2b(v.x) | ((u32)f2b(v.y) << 16);
    pk[2*i+1] = (u32)f2b(v.z) | ((u32)f2b(v.w) << 16);
  }
  uint4* drow = (uint4*)(ea2 + (size_t)e * 32);
  drow[0] = make_uint4(pk[0], pk[1], pk[2], pk[3]);
  drow[1] = make_uint4(pk[4], pk[5], pk[6], pk[7]);
  drow[2] = make_uint4(pk[8], pk[9], pk[10], pk[11]);
  drow[3] = make_uint4(pk[12], pk[13], pk[14], pk[15]);
}

// hierarchical scan; block 0 also zeroes the pad tails (replaces 3 memsets)
__global__ __launch_bounds__(256) void k_scan1(const int* __restrict__ deg, int* __restrict__ bsum, int n,
                                               int* __restrict__ ssrc, int* __restrict__ sdst,
                                               u16* __restrict__ ea2s_pad, int E){
  int b = blockIdx.x, t = threadIdx.x, lane = t & 63, wv = t >> 6;
  if (b == 0){
    if (t < 64){ ssrc[E + t] = 0; sdst[E + t] = 0; }
    ((uint4*)ea2s_pad)[t] = make_uint4(0, 0, 0, 0);   // 256 * 16B = 4 KB pad rows
  }
  int i0 = b * 1024 + t * 4;
  int4 v = make_int4(0,0,0,0);
  if (i0 + 3 < n) v = *(const int4*)(deg + i0);
  else { if (i0 < n) v.x = deg[i0]; if (i0+1 < n) v.y = deg[i0+1]; if (i0+2 < n) v.z = deg[i0+2]; }
  int s = v.x + v.y + v.z + v.w;
  #pragma unroll
  for (int off = 1; off < 64; off <<= 1) s += __shfl_xor(s, off);
  __shared__ int ws[4];
  if (lane == 0) ws[wv] = s;
  __syncthreads();
  if (t == 0) bsum[b] = ws[0] + ws[1] + ws[2] + ws[3];
}

__global__ __launch_bounds__(1024) void k_scan2(int* __restrict__ bsum, int nb, int* __restrict__ segN){
  int t = threadIdx.x, lane = t & 63, w = t >> 6;
  int v = (t < nb) ? bsum[t] : 0;
  int x = v;
  #pragma unroll
  for (int off = 1; off < 64; off <<= 1){
    int y = __shfl_up(x, off);
    if (lane >= off) x += y;
  }
  __shared__ int wsum[16];
  if (lane == 63) wsum[w] = x;
  __syncthreads();
  if (w == 0 && lane < 16){
    int sv = wsum[lane];
    #pragma unroll
    for (int off = 1; off < 16; off <<= 1){
      int y = __shfl_up(sv, off);
      if (lane >= off) sv += y;
    }
    wsum[lane] = sv;
  }
  __syncthreads();
  int woff = (w > 0) ? wsum[w - 1] : 0;
  if (t < nb) bsum[t] = woff + x - v;
  if (t == 0) *segN = wsum[15];
}

__global__ __launch_bounds__(256) void k_scan3(const int* __restrict__ deg, const int* __restrict__ bsum,
                                               int* __restrict__ seg, int n){
  int b = blockIdx.x, t = threadIdx.x, lane = t & 63, wv = t >> 6;
  int i0 = b * 1024 + t * 4;
  int4 v = make_int4(0,0,0,0);
  if (i0 + 3 < n) v = *(const int4*)(deg + i0);
  else { if (i0 < n) v.x = deg[i0]; if (i0+1 < n) v.y = deg[i0+1]; if (i0+2 < n) v.z = deg[i0+2]; }
  int s = v.x + v.y + v.z + v.w;
  int x = s;
  #pragma unroll
  for (int off = 1; off < 64; off <<= 1){
    int y = __shfl_up(x, off);
    if (lane >= off) x += y;
  }
  __shared__ int ws[4];
  if (lane == 63) ws[wv] = x;
  __syncthreads();
  int woff = 0;
  #pragma unroll
  for (int k = 0; k < 4; k++) if (k < wv) woff += ws[k];
  int base = bsum[b] + woff + (x - s);
  if (i0 < n)     seg[i0]     = base;
  if (i0+1 < n)   seg[i0+1]   = base + v.x;
  if (i0+2 < n)   seg[i0+2]   = base + v.x + v.y;
  if (i0+3 < n)   seg[i0+3]   = base + v.x + v.y + v.z;
}

// scatter: 12B {src, dst, eid} per edge to sorted position
__global__ void k_scatter(const int* __restrict__ src, const int* __restrict__ dst,
                          const int* __restrict__ seg, int* __restrict__ cur,
                          int* __restrict__ ssrc, int* __restrict__ sdst,
                          int* __restrict__ seid, int E){
  int e = blockIdx.x * blockDim.x + threadIdx.x;
  if (e >= E) return;
  int d = dst[e];
  int pos = seg[d] + atomicAdd(&cur[d], 1);
  ssrc[pos] = src[e];
  sdst[pos] = d;
  seid[pos] = e;
}

// sort bf16 ea2 into dst-sorted order: random 64B row reads, coalesced writes
__global__ void k_sortb(const int* __restrict__ seid, const u16* __restrict__ ea2o,
                        u16* __restrict__ ea2s, int E){
  int t = blockIdx.x * blockDim.x + threadIdx.x;
  int e = t >> 2, j = t & 3;
  if (e >= E) return;
  int eid = seid[e];
  uint4 v = *(const uint4*)(ea2o + (size_t)eid * 32 + j * 8);
  *(uint4*)(ea2s + (size_t)e * 32 + j * 8) = v;
}

// ---------- W prep: transpose + bf16 hi/lo split ----------
__global__ __launch_bounds__(256) void k_prepw(
    const float* __restrict__ W0, const float* __restrict__ W1, const float* __restrict__ W2,
    const float* __restrict__ W3, const float* __restrict__ W4, const float* __restrict__ W5,
    u16* __restrict__ WtH, u16* __restrict__ WtL)
{
  int mat = blockIdx.z;
  const float* W = (mat == 0) ? W0 : (mat == 1) ? W1 : (mat == 2) ? W2 :
                   (mat == 3) ? W3 : (mat == 4) ? W4 : W5;
  __shared__ float tile[32][33];
  int kt = blockIdx.x * 32, ct = blockIdx.y * 32;
  int tr = threadIdx.x & 31, ti = threadIdx.x >> 5;
  #pragma unroll
  for (int j = 0; j < 4; j++){
    int kk = ti + 8 * j;
    tile[kk][tr] = W[(size_t)(kt + kk) * 128 + ct + tr];
  }
  __syncthreads();
  #pragma unroll
  for (int j = 0; j < 4; j++){
    int cc = ti + 8 * j;
    float v = tile[tr][cc];
    u16 hi = f2b(v);
    u16 lo = f2b(v - b2f(hi));
    size_t o = (size_t)mat * 16384 + (size_t)(ct + cc) * 128 + kt + tr;
    WtH[o] = hi;
    WtL[o] = lo;
  }
}

// ---------- node transform via MFMA (bf16x3 split) ----------
__global__ __launch_bounds__(256) void k_gemm2(
    const float* __restrict__ A,
    const u16* __restrict__ WtH, const u16* __restrict__ WtL,
    u16* __restrict__ xlb, u16* __restrict__ xrb, int nrows)
{
  __shared__ u16 sAH[64][72], sAL[64][72];
  __shared__ u16 sWH[128][72], sWL[128][72];
  int t = threadIdx.x, wv = t >> 6, lane = t & 63;
  int col = lane & 15, kg = lane >> 4;
  int r0 = blockIdx.x * 64;
  int mat = blockIdx.y;
  const u16* WHb = WtH + (size_t)mat * 16384;
  const u16* WLb = WtL + (size_t)mat * 16384;

  f32x4 acc[4][2];
  #pragma unroll
  for (int m = 0; m < 4; m++)
    #pragma unroll
    for (int n = 0; n < 2; n++)
      acc[m][n] = (f32x4){0.f, 0.f, 0.f, 0.f};

  int ar = t >> 2, ak = (t & 3) << 4;
  int wc = t >> 1, wk = (t & 1) << 5;

  for (int kh = 0; kh < 2; kh++){
    __syncthreads();
    {
      int gr = r0 + ar;
      const float* ap = A + (size_t)gr * 128 + kh * 64 + ak;
      float4 va = {0,0,0,0}, vb = {0,0,0,0}, vc = {0,0,0,0}, vd = {0,0,0,0};
      if (gr < nrows){
        va = *(const float4*)ap; vb = *(const float4*)(ap + 4);
        vc = *(const float4*)(ap + 8); vd = *(const float4*)(ap + 12);
      }
      float fv[16] = { va.x, va.y, va.z, va.w, vb.x, vb.y, vb.z, vb.w,
                       vc.x, vc.y, vc.z, vc.w, vd.x, vd.y, vd.z, vd.w };
      u32 hp[8], lp[8];
      #pragma unroll
      for (int i = 0; i < 8; i++){
        u16 h0 = f2b(fv[2*i]),   h1 = f2b(fv[2*i+1]);
        u16 l0 = f2b(fv[2*i]   - b2f(h0));
        u16 l1 = f2b(fv[2*i+1] - b2f(h1));
        hp[i] = (u32)h0 | ((u32)h1 << 16);
        lp[i] = (u32)l0 | ((u32)l1 << 16);
      }
      *(uint4*)&sAH[ar][ak]     = make_uint4(hp[0], hp[1], hp[2], hp[3]);
      *(uint4*)&sAH[ar][ak + 8] = make_uint4(hp[4], hp[5], hp[6], hp[7]);
      *(uint4*)&sAL[ar][ak]     = make_uint4(lp[0], lp[1], lp[2], lp[3]);
      *(uint4*)&sAL[ar][ak + 8] = make_uint4(lp[4], lp[5], lp[6], lp[7]);
    }
    {
      const u16* gh = WHb + (size_t)wc * 128 + kh * 64 + wk;
      const u16* gl = WLb + (size_t)wc * 128 + kh * 64 + wk;
      uint4 h0 = *(const uint4*)gh, h1 = *(const uint4*)(gh + 8);
      uint4 h2 = *(const uint4*)(gh + 16), h3 = *(const uint4*)(gh + 24);
      uint4 l0 = *(const uint4*)gl, l1 = *(const uint4*)(gl + 8);
      uint4 l2 = *(const uint4*)(gl + 16), l3 = *(const uint4*)(gl + 24);
      *(uint4*)&sWH[wc][wk]      = h0; *(uint4*)&sWH[wc][wk + 8]  = h1;
      *(uint4*)&sWH[wc][wk + 16] = h2; *(uint4*)&sWH[wc][wk + 24] = h3;
      *(uint4*)&sWL[wc][wk]      = l0; *(uint4*)&sWL[wc][wk + 8]  = l1;
      *(uint4*)&sWL[wc][wk + 16] = l2; *(uint4*)&sWL[wc][wk + 24] = l3;
    }
    __syncthreads();
    #pragma unroll
    for (int ks = 0; ks < 2; ks++){
      bf16x8 bhi0 = *(const bf16x8*)&sWH[wv*32 + col]     [ks*32 + kg*8];
      bf16x8 bhi1 = *(const bf16x8*)&sWH[wv*32 + 16 + col][ks*32 + kg*8];
      bf16x8 blo0 = *(const bf16x8*)&sWL[wv*32 + col]     [ks*32 + kg*8];
      bf16x8 blo1 = *(const bf16x8*)&sWL[wv*32 + 16 + col][ks*32 + kg*8];
      #pragma unroll
      for (int m = 0; m < 4; m++){
        bf16x8 ahv = *(const bf16x8*)&sAH[m*16 + col][ks*32 + kg*8];
        bf16x8 alv = *(const bf16x8*)&sAL[m*16 + col][ks*32 + kg*8];
        acc[m][0] = __builtin_amdgcn_mfma_f32_16x16x32_bf16(ahv, bhi0, acc[m][0], 0, 0, 0);
        acc[m][0] = __builtin_amdgcn_mfma_f32_16x16x32_bf16(alv, bhi0, acc[m][0], 0, 0, 0);
        acc[m][0] = __builtin_amdgcn_mfma_f32_16x16x32_bf16(ahv, blo0, acc[m][0], 0, 0, 0);
        acc[m][1] = __builtin_amdgcn_mfma_f32_16x16x32_bf16(ahv, bhi1, acc[m][1], 0, 0, 0);
        acc[m][1] = __builtin_amdgcn_mfma_f32_16x16x32_bf16(alv, bhi1, acc[m][1], 0, 0, 0);
        acc[m][1] = __builtin_amdgcn_mfma_f32_16x16x32_bf16(ahv, blo1, acc[m][1], 0, 0, 0);
      }
    }
  }
  u16* ob = mat ? xrb : xlb;
  #pragma unroll
  for (int m = 0; m < 4; m++){
    #pragma unroll
    for (int n = 0; n < 2; n++){
      #pragma unroll
      for (int r = 0; r < 4; r++){
        int row = r0 + m*16 + kg*4 + r;
        int c   = wv*32 + n*16 + col;
        if (row < nrows) ob[(size_t)row * 128 + c] = f2b(acc[m][n][r]);
      }
    }
  }
}

// ---------- edge kernel: sorted streaming ea2s; MFMA + LDS bounce; xj 2-deep, xi single ----------
__global__ __launch_bounds__(256) void k_edge(
    const int* __restrict__ ssrc, const int* __restrict__ sdst,
    const u16* __restrict__ ea2s,
    const u16* __restrict__ xlb, const u16* __restrict__ xrb,
    const float* __restrict__ We, const float* __restrict__ att,
    float2* __restrict__ pr2, int ntiles, int E)
{
  __shared__ float sD[4][16][132];
  int wv = threadIdx.x >> 6, lane = threadIdx.x & 63;
  int col = lane & 15, kg = lane >> 4;
  int er = lane >> 2, q = lane & 3;

  bf16x8 bw[8];
  #pragma unroll
  for (int c = 0; c < 8; c++)
    #pragma unroll
    for (int j = 0; j < 8; j++)
      bw[c][j] = (short)f2b(We[(kg * 8 + j) * 128 + c * 16 + col]);
  u32 attp[16];
  #pragma unroll
  for (int i = 0; i < 16; i++)
    attp[i] = (u32)f2b(att[q * 32 + 2*i]) | ((u32)f2b(att[q * 32 + 2*i + 1]) << 16);

  int nw = gridDim.x * 4;
  int t = blockIdx.x * 4 + wv;
  if (t >= ntiles) return;

  // prologue: tile t loads (ea2s streamed; xj prefetched; xi loaded per-iteration)
  int e0 = t * 16;
  bf16x8 a = *(const bf16x8*)(ea2s + (size_t)(e0 + col) * 32 + kg * 8);
  int p = e0 + er;
  int sn = ssrc[p], dn = sdst[p];
  const u16* xjp = xlb + (size_t)sn * 128 + q * 32;
  uint4 j0 = ((const uint4*)xjp)[0], j1 = ((const uint4*)xjp)[1],
        j2 = ((const uint4*)xjp)[2], j3 = ((const uint4*)xjp)[3];

  while (true){
    // current-tile xi loads (dst-sorted -> mostly L1-resident), issued at loop top
    const u16* xip = xrb + (size_t)dn * 128 + q * 32;
    uint4 i0 = ((const uint4*)xip)[0], i1 = ((const uint4*)xip)[1],
          i2 = ((const uint4*)xip)[2], i3 = ((const uint4*)xip)[3];

    // next-tile prefetches
    int t2 = t + nw;
    bool more = (t2 < ntiles);
    int tc = more ? t2 : t;
    int e02 = tc * 16;
    int p2 = e02 + er;
    int sn2 = ssrc[p2], dn2 = sdst[p2];
    bf16x8 a2 = *(const bf16x8*)(ea2s + (size_t)(e02 + col) * 32 + kg * 8);
    const u16* xj2 = xlb + (size_t)sn2 * 128 + q * 32;
    uint4 nj0 = ((const uint4*)xj2)[0], nj1 = ((const uint4*)xj2)[1],
          nj2 = ((const uint4*)xj2)[2], nj3 = ((const uint4*)xj2)[3];

    // MFMA current tile -> LDS
    #pragma unroll
    for (int c = 0; c < 8; c++){
      f32x4 d = __builtin_amdgcn_mfma_f32_16x16x32_bf16(a, bw[c], (f32x4){0.f,0.f,0.f,0.f}, 0, 0, 0);
      #pragma unroll
      for (int r = 0; r < 4; r++)
        sD[wv][kg * 4 + r][c * 16 + col] = d[r];
    }

    // epilogue current tile
    const float* drow = &sD[wv][er][q * 32];
    float acc = 0.f;
#define EPK(KO, JQ, IQ) { \
    float4 d0 = *(const float4*)(drow + KO*8); \
    float4 d1 = *(const float4*)(drow + KO*8 + 4); \
    float v; u32 jw, iw, aw; \
    jw = JQ.x; iw = IQ.x; aw = attp[KO*4+0]; \
    v = d0.x + bl(jw) + bl(iw); v = fmaxf(v, 0.2f*v); acc = fmaf(v, bl(aw), acc); \
    v = d0.y + bh(jw) + bh(iw); v = fmaxf(v, 0.2f*v); acc = fmaf(v, bh(aw), acc); \
    jw = JQ.y; iw = IQ.y; aw = attp[KO*4+1]; \
    v = d0.z + bl(jw) + bl(iw); v = fmaxf(v, 0.2f*v); acc = fmaf(v, bl(aw), acc); \
    v = d0.w + bh(jw) + bh(iw); v = fmaxf(v, 0.2f*v); acc = fmaf(v, bh(aw), acc); \
    jw = JQ.z; iw = IQ.z; aw = attp[KO*4+2]; \
    v = d1.x + bl(jw) + bl(iw); v = fmaxf(v, 0.2f*v); acc = fmaf(v, bl(aw), acc); \
    v = d1.y + bh(jw) + bh(iw); v = fmaxf(v, 0.2f*v); acc = fmaf(v, bh(aw), acc); \
    jw = JQ.w; iw = IQ.w; aw = attp[KO*4+3]; \
    v = d1.z + bl(jw) + bl(iw); v = fmaxf(v, 0.2f*v); acc = fmaf(v, bl(aw), acc); \
    v = d1.w + bh(jw) + bh(iw); v = fmaxf(v, 0.2f*v); acc = fmaf(v, bh(aw), acc); }
    EPK(0, j0, i0) EPK(1, j1, i1) EPK(2, j2, i2) EPK(3, j3, i3)
#undef EPK
    acc += __shfl_xor(acc, 1);
    float other = __shfl_xor(acc, 2);
    if (q == 0 && p < E){
      pr2[p] = make_float2(__expf(fminf(acc, 80.f)), __expf(fminf(other, 80.f)));
    }
    if (!more) break;
    t = t2; p = p2; dn = dn2; a = a2;
    j0 = nj0; j1 = nj1; j2 = nj2; j3 = nj3;
  }
}

// ---------- per-node reduce: 4 edges/step across wave, 16B lanes, 2-deep pipeline ----------
// lane = (eg = lane>>4 edge slot, cb = lane&15 channel block of 8); shfl_xor(16,32) reduces eg.
template<int RELU>
__global__ __launch_bounds__(256) void k_seg2(
    const int* __restrict__ seg, const int* __restrict__ ssrc,
    const float2* __restrict__ pr2,
    const u16* __restrict__ xlb, const float* __restrict__ bias,
    float* __restrict__ out, int N)
{
  int wid  = blockIdx.x * 4 + (threadIdx.x >> 6);
  int lane = threadIdx.x & 63;
  if (wid >= N) return;
  int eg = lane >> 4, cb = lane & 15, c0 = cb * 8;
  int hsel = cb >> 3;

  int p0 = seg[wid], p1 = seg[wid + 1];
  float s = 0.f;
  float o0 = 0.f, o1 = 0.f, o2 = 0.f, o3 = 0.f, o4 = 0.f, o5 = 0.f, o6 = 0.f, o7 = 0.f;

  if (p0 < p1){
#define LDB(PP, QV, XV) { \
    int ii = PP + eg; ii = (ii < p1) ? ii : (p1 - 1); \
    int sn = ssrc[ii]; \
    QV = pr2[ii]; \
    XV = *(const uint4*)(xlb + (size_t)sn * 128 + c0); }
    float2 qa; uint4 xa;
    LDB(p0, qa, xa)
    int p = p0;
    while (true){
      int pn = p + 4;
      bool more = pn < p1;
      int pc = more ? pn : p;
      float2 qb; uint4 xb;
      LDB(pc, qb, xb)
      float e = hsel ? qa.y : qa.x;
      if (p + eg >= p1) e = 0.f;
      s += e;
      o0 = fmaf(e, bl(xa.x), o0); o1 = fmaf(e, bh(xa.x), o1);
      o2 = fmaf(e, bl(xa.y), o2); o3 = fmaf(e, bh(xa.y), o3);
      o4 = fmaf(e, bl(xa.z), o4); o5 = fmaf(e, bh(xa.z), o5);
      o6 = fmaf(e, bl(xa.w), o6); o7 = fmaf(e, bh(xa.w), o7);
      if (!more) break;
      p = pn; qa = qb; xa = xb;
    }
#undef LDB
  }
  s  += __shfl_xor(s, 16);  s  += __shfl_xor(s, 32);
  o0 += __shfl_xor(o0, 16); o0 += __shfl_xor(o0, 32);
  o1 += __shfl_xor(o1, 16); o1 += __shfl_xor(o1, 32);
  o2 += __shfl_xor(o2, 16); o2 += __shfl_xor(o2, 32);
  o3 += __shfl_xor(o3, 16); o3 += __shfl_xor(o3, 32);
  o4 += __shfl_xor(o4, 16); o4 += __shfl_xor(o4, 32);
  o5 += __shfl_xor(o5, 16); o5 += __shfl_xor(o5, 32);
  o6 += __shfl_xor(o6, 16); o6 += __shfl_xor(o6, 32);
  o7 += __shfl_xor(o7, 16); o7 += __shfl_xor(o7, 32);

  if (eg == 0){
    float inv = 1.0f / (s + 1e-16f);
    float4 b0 = *(const float4*)(bias + c0);
    float4 b1 = *(const float4*)(bias + c0 + 4);
    float r0 = fmaf(o0, inv, b0.x), r1 = fmaf(o1, inv, b0.y);
    float r2 = fmaf(o2, inv, b0.z), r3 = fmaf(o3, inv, b0.w);
    float r4 = fmaf(o4, inv, b1.x), r5 = fmaf(o5, inv, b1.y);
    float r6 = fmaf(o6, inv, b1.z), r7 = fmaf(o7, inv, b1.w);
    if (RELU){
      r0 = fmaxf(r0, 0.f); r1 = fmaxf(r1, 0.f); r2 = fmaxf(r2, 0.f); r3 = fmaxf(r3, 0.f);
      r4 = fmaxf(r4, 0.f); r5 = fmaxf(r5, 0.f); r6 = fmaxf(r6, 0.f); r7 = fmaxf(r7, 0.f);
    }
    *(float4*)(out + (size_t)wid * 128 + c0)     = make_float4(r0, r1, r2, r3);
    *(float4*)(out + (size_t)wid * 128 + c0 + 4) = make_float4(r4, r5, r6, r7);
  }
}

// ---------- launch ----------
extern "C" void kernel_launch(void* const* d_in, const int* in_sizes, int n_in,
                              void* d_out, int out_size, void* d_ws, size_t ws_size,
                              hipStream_t stream)
{
  const float* x     = (const float*)d_in[0];
  const int*   ei    = (const int*)  d_in[1];
  const float* eattr = (const float*)d_in[2];
  const float* Wp[3][5];
  for (int l = 0; l < 3; l++)
    for (int j = 0; j < 5; j++)
      Wp[l][j] = (const float*)d_in[3 + l * 5 + j];

  int N = in_sizes[0] / 128;
  int E = in_sizes[2] / 32;

  char* w = (char*)d_ws;
  auto alloc = [&](size_t bytes) -> char* {
    char* p = w; w += (bytes + 255) & ~(size_t)255; return p;
  };
  float* xr   = (float*)alloc((size_t)N * 128 * 4);   // inter-layer h buffer
  u16*   xlb  = (u16*)  alloc((size_t)N * 128 * 2);
  u16*   xrb  = (u16*)  alloc((size_t)N * 128 * 2);
  u16*   ea2o = (u16*)  alloc((size_t)E * 32 * 2);           // original order bf16
  u16*   ea2s = (u16*)  alloc((size_t)(E + 64) * 32 * 2);    // dst-sorted bf16
  float2* prb = (float2*)alloc((size_t)E * 8);
  u16*   WtH  = (u16*)  alloc((size_t)6 * 16384 * 2);
  u16*   WtL  = (u16*)  alloc((size_t)6 * 16384 * 2);
  int* srcA   = (int*)alloc((size_t)E * 4);
  int* dstA   = (int*)alloc((size_t)E * 4);
  int* ssrc   = (int*)alloc((size_t)(E + 64) * 4);
  int* sdst   = (int*)alloc((size_t)(E + 64) * 4);
  int* seid   = (int*)alloc((size_t)E * 4);
  int* seg    = (int*)alloc((size_t)(N + 1) * 4);
  int* bsum   = (int*)alloc(1024 * 4);
  // deg, cur, flag contiguous -> single memset covers all three (incl. alignment pads)
  char* zbase = alloc((size_t)N * 4);      int* deg  = (int*)zbase;
  char* zcur  = alloc((size_t)N * 4);      int* cur  = (int*)zcur;
  char* zflag = alloc(256);                u32* flag = (u32*)zflag;
  size_t zspan = (size_t)(zflag + 256 - zbase);

  hipMemsetAsync(zbase, 0, zspan, stream);

  int ndet = (E < 16384) ? E : 16384;
  k_detect<<<(ndet + 255) / 256, 256, 0, stream>>>((const u32*)ei, ndet, flag);
  int gE = (E + 255) / 256;
  k_convhist<<<gE, 256, 0, stream>>>(ei, srcA, dstA, deg, eattr, ea2o, E, flag);
  int nb = (N + 1023) / 1024;
  k_scan1<<<nb, 256, 0, stream>>>(deg, bsum, N, ssrc, sdst, ea2s + (size_t)E * 32, E);
  k_scan2<<<1, 1024, 0, stream>>>(bsum, nb, seg + N);
  k_scan3<<<nb, 256, 0, stream>>>(deg, bsum, seg, N);
  k_scatter<<<gE, 256, 0, stream>>>(srcA, dstA, seg, cur, ssrc, sdst, seid, E);
  k_sortb<<<(E * 4 + 255) / 256, 256, 0, stream>>>(seid, ea2o, ea2s, E);
  dim3 gp(4, 4, 6);
  k_prepw<<<gp, 256, 0, stream>>>(Wp[0][0], Wp[0][1], Wp[1][0], Wp[1][1], Wp[2][0], Wp[2][1], WtH, WtL);

  int gS = (N + 3) / 4;
  int ntiles = (E + 15) / 16;
  int gEdge = (ntiles + 3) / 4; if (gEdge > 2048) gEdge = 2048;
  dim3 gG2((N + 63) / 64, 2);

  const float* hin = x;
  for (int l = 0; l < 3; l++){
    k_gemm2<<<gG2, 256, 0, stream>>>(hin, WtH + (size_t)l * 2 * 16384, WtL + (size_t)l * 2 * 16384, xlb, xrb, N);
    k_edge<<<gEdge, 256, 0, stream>>>(ssrc, sdst, ea2s, xlb, xrb, Wp[l][2], Wp[l][3], prb, ntiles, E);
    float* outp = (l == 2) ? (float*)d_out : xr;
    if (l == 2) k_seg2<0><<<gS, 256, 0, stream>>>(seg, ssrc, prb, xlb, Wp[l][4], outp, N);
    else        k_seg2<1><<<gS, 256, 0, stream>>>(seg, ssrc, prb, xlb, Wp[l][4], outp, N);
    hin = xr;
  }
}